// Round 15
// baseline (29.246 us; speedup 1.0000x reference)
//
#include <hip/hip_runtime.h>
#include <hip/hip_bf16.h>
#include <math.h>
#include <stdint.h>

namespace {

typedef __bf16 bf16x8 __attribute__((ext_vector_type(8)));
typedef float f32x4 __attribute__((ext_vector_type(4)));

constexpr int L = 64;
constexpr int DH = 64;

// Swizzle key: distinct across BOTH stride-1 and stride-4 row sequences.
__device__ __forceinline__ int kkey(int r) { return (r ^ (r >> 2)) & 7; }
// bf16 tile (V^T, C): byte offset of (row,col), 128B rows, 16B-slot XOR.
__device__ __forceinline__ int swz(int row, int col) {
  return row * 128 + ((((col >> 3) ^ kkey(row)) & 7) << 4) + (col & 7) * 2;
}

__device__ __forceinline__ unsigned short bfbits(float f) {
  __bf16 h = (__bf16)f;
  return __builtin_bit_cast(unsigned short, h);
}
__device__ __forceinline__ __bf16 tobf(float f) { return (__bf16)f; }
__device__ __forceinline__ unsigned long long pack4(float a, float b, float c,
                                                    float d) {
  return (unsigned long long)bfbits(a) | ((unsigned long long)bfbits(b) << 16) |
         ((unsigned long long)bfbits(c) << 32) |
         ((unsigned long long)bfbits(d) << 48);
}

// Direct global->LDS DMA, 16B per lane (LDS dest = uniform base + lane*16).
__device__ __forceinline__ void gload16(const float* gsrc, float* ldst) {
  __builtin_amdgcn_global_load_lds(
      (const __attribute__((address_space(1))) uint32_t*)gsrc,
      (__attribute__((address_space(3))) uint32_t*)ldst, 16, 0, 0);
}

// One wave = one chunk (R8 base, best=26.9us). The untried corner:
// LOW per-wave wall (Q via pipelined DMA, its 16 reg-loads + pack +
// ds_write pass deleted) AND HIGH residency (LDS only 24KB: Q fp32 16KB
// reused for C after mm1, V^T bf16 8KB) -> 6 blocks/CU with natural
// block-turnover pipelining. K,V stay direct reg loads (K fragment-order
// was never the binder: R6==R2; V needs the reg path for transpose).
__global__ __launch_bounds__(64, 2) void mlstm_mfma(
    const float* __restrict__ q, const float* __restrict__ k,
    const float* __restrict__ v, const float* __restrict__ ig,
    const float* __restrict__ fg, float* __restrict__ out) {

  __shared__ __align__(16) float q_lds[64 * 64];   // fp32 Q (slot-swz); low 8KB reused for C
  __shared__ __align__(16) char vt_raw[64 * 128];  // V^T bf16, swizzled

  const int lane = threadIdx.x;
  const int m = lane & 15;   // fragment row/col index
  const int g = lane >> 4;   // fragment k-group
  const int rsub = lane >> 4;
  const int slot = lane & 15;
  const size_t cbase = (size_t)blockIdx.x * (L * DH);
  const size_t gb = (size_t)blockIdx.x * L;

  // ======== phase 0: gates -> V reg loads -> Q DMA -> K reg loads ========
  const float fgv = fg[gb + lane];
  const float igv = ig[gb + lane];

  const float4* v4 = (const float4*)(v + cbase);
  float4 vbuf[16];
#pragma unroll
  for (int it = 0; it < 16; ++it) vbuf[it] = v4[it * 64 + lane];

  // Q -> LDS DMA, source pre-swizzled (R10/R11-validated mapping).
#pragma unroll
  for (int it = 0; it < 16; ++it) {
    const int r = it * 4 + rsub;
    const int coff = r * 64 + ((slot ^ kkey(r)) << 2);
    gload16(q + cbase + coff, &q_lds[it * 256]);
  }

  // K fragment-order reg loads (R6/R8 path).
  float4 kbuf[16];
#pragma unroll
  for (int rb = 0; rb < 4; ++rb)
#pragma unroll
    for (int kb = 0; kb < 2; ++kb) {
      const int off = (rb * 16 + m) * 64 + kb * 32 + g * 8;
      kbuf[rb * 4 + kb * 2 + 0] = *(const float4*)(k + cbase + off);
      kbuf[rb * 4 + kb * 2 + 1] = *(const float4*)(k + cbase + off + 4);
    }

  // ======== gate scan (needs only the first two loads) ====================
  float ea, eb, em;  // lane l holds values for time index l
  {
    const float lf = fminf(fgv, 0.f) - log1pf(__expf(-fabsf(fgv)));
    float cum = lf;
#pragma unroll
    for (int o = 1; o < 64; o <<= 1) {
      const float t = __shfl_up(cum, o, 64);
      if (lane >= o) cum += t;
    }
    const float a = igv - cum;
    float b = a;
#pragma unroll
    for (int o = 1; o < 64; o <<= 1) {
      const float t = __shfl_up(b, o, 64);
      if (lane >= o) b = fmaxf(b, t);
    }
    const float bmax = __shfl(b, 63, 64);
    ea = 0.125f * __expf(a - bmax);  // fold 1/sqrt(DH)
    eb = __expf(bmax - b);
    em = __expf(-(b + cum));
  }

  // ======== V^T scatter into LDS (bf16, swizzled) =========================
  {
    unsigned short* vt = (unsigned short*)vt_raw;
#pragma unroll
    for (int it = 0; it < 16; ++it) {
      const int idx = it * 64 + lane;  // float4 index in the chunk
      const int j = idx >> 4;          // time index
      const int d0 = (idx & 15) * 4;   // feature
      vt[swz(d0 + 0, j) >> 1] = bfbits(vbuf[it].x);
      vt[swz(d0 + 1, j) >> 1] = bfbits(vbuf[it].y);
      vt[swz(d0 + 2, j) >> 1] = bfbits(vbuf[it].z);
      vt[swz(d0 + 3, j) >> 1] = bfbits(vbuf[it].w);
    }
  }

  // ======== V^T fragments (in-order after scatter, own wave) ==============
  bf16x8 vfr[4][2];
#pragma unroll
  for (int db = 0; db < 4; ++db)
#pragma unroll
    for (int jb = 0; jb < 2; ++jb)
      vfr[db][jb] =
          *(const bf16x8*)(vt_raw + swz(db * 16 + m, jb * 32 + g * 8));

  // ======== cvt K fragments ===============================================
  bf16x8 kf[4][2];
#pragma unroll
  for (int rb = 0; rb < 4; ++rb)
#pragma unroll
    for (int kb = 0; kb < 2; ++kb) {
      const float4 k0 = kbuf[rb * 4 + kb * 2 + 0];
      const float4 k1 = kbuf[rb * 4 + kb * 2 + 1];
      kf[rb][kb] = bf16x8{tobf(k0.x), tobf(k0.y), tobf(k0.z), tobf(k0.w),
                          tobf(k1.x), tobf(k1.y), tobf(k1.z), tobf(k1.w)};
    }

  // ======== drain Q DMA, then Q fragments from fp32 LDS + cvt =============
  asm volatile("s_waitcnt vmcnt(0)" ::: "memory");

  bf16x8 qf[4][2];
#pragma unroll
  for (int rb = 0; rb < 4; ++rb)
#pragma unroll
    for (int kb = 0; kb < 2; ++kb) {
      const int row = rb * 16 + m;
      const int c4 = kb * 8 + g * 2;
      const int o0 = row * 64 + (((c4 + 0) ^ kkey(row)) << 2);
      const int o1 = row * 64 + (((c4 + 1) ^ kkey(row)) << 2);
      const f32x4 qa = *(const f32x4*)&q_lds[o0];
      const f32x4 qb = *(const f32x4*)&q_lds[o1];
      qf[rb][kb] = bf16x8{tobf(qa[0]), tobf(qa[1]), tobf(qa[2]), tobf(qa[3]),
                          tobf(qb[0]), tobf(qb[1]), tobf(qb[2]), tobf(qb[3])};
    }

  // ======== gate lookups ==================================================
  float ea_j[4][4];
#pragma unroll
  for (int rb = 0; rb < 4; ++rb)
#pragma unroll
    for (int e = 0; e < 4; ++e)
      ea_j[rb][e] = __shfl(ea, rb * 16 + g * 4 + e, 64);

  // ======== per-cb: mm1 (rb<=cb), gating, C write over Q tile, norm =======
  char* cs_raw = (char*)q_lds;  // Q frags fully consumed; same-array WAR
  float invr[4];
#pragma unroll
  for (int cb = 0; cb < 4; ++cb) {
    f32x4 st[4];
#pragma unroll
    for (int rb = 0; rb < 4; ++rb) {
      if (rb <= cb) {
        f32x4 acc = {0.f, 0.f, 0.f, 0.f};
        acc = __builtin_amdgcn_mfma_f32_16x16x32_bf16(kf[rb][0], qf[cb][0], acc, 0, 0, 0);
        acc = __builtin_amdgcn_mfma_f32_16x16x32_bf16(kf[rb][1], qf[cb][1], acc, 0, 0, 0);
        st[rb] = acc;
      }
    }
    const int i = cb * 16 + m;
    const float ebv = __shfl(eb, i, 64);
    const float emv = __shfl(em, i, 64);
    float rs = 0.f;
    const int rbfill = cb | 1;  // zero-fill the jb ranges mm2 will read
#pragma unroll
    for (int rb = 0; rb < 4; ++rb) {
      if (rb > rbfill) continue;
      unsigned long long wp = 0ull;
      if (rb <= cb) {
        float vv[4];
#pragma unroll
        for (int e = 0; e < 4; ++e) {
          const int j = rb * 16 + g * 4 + e;
          vv[e] = (j <= i) ? st[rb][e] * ea_j[rb][e] * ebv : 0.f;
          rs += vv[e];
        }
        wp = pack4(vv[0], vv[1], vv[2], vv[3]);
      }
      *(unsigned long long*)(cs_raw + swz(i, rb * 16 + g * 4)) = wp;
    }
    rs += __shfl_xor(rs, 16, 64);
    rs += __shfl_xor(rs, 32, 64);
    invr[cb] = 1.f / (fmaxf(fabsf(rs), emv) + 1e-6f);
  }

  // ======== mm2 (per-ib): H^T = V^T * C^T, scale + store ===================
#pragma unroll
  for (int ib = 0; ib < 4; ++ib) {
    const int i = ib * 16 + m;
    const bf16x8 c0 = *(const bf16x8*)(cs_raw + swz(i, g * 8));
    f32x4 acc[4];
#pragma unroll
    for (int db = 0; db < 4; ++db) {
      f32x4 z = {0.f, 0.f, 0.f, 0.f};
      acc[db] = __builtin_amdgcn_mfma_f32_16x16x32_bf16(vfr[db][0], c0, z, 0, 0, 0);
    }
    if (ib >= 2) {
      const bf16x8 c1 = *(const bf16x8*)(cs_raw + swz(i, 32 + g * 8));
#pragma unroll
      for (int db = 0; db < 4; ++db)
        acc[db] = __builtin_amdgcn_mfma_f32_16x16x32_bf16(vfr[db][1], c1, acc[db], 0, 0, 0);
    }
    const float iv = invr[ib];
    float* op = out + cbase + i * 64 + g * 4;
#pragma unroll
    for (int db = 0; db < 4; ++db) {
      const f32x4 hv = acc[db];
      *(float4*)(op + db * 16) =
          make_float4(hv[0] * iv, hv[1] * iv, hv[2] * iv, hv[3] * iv);
    }
  }
}

}  // namespace

extern "C" void kernel_launch(void* const* d_in, const int* in_sizes, int n_in,
                              void* d_out, int out_size, void* d_ws,
                              size_t ws_size, hipStream_t stream) {
  const float* q = (const float*)d_in[0];
  const float* k = (const float*)d_in[1];
  const float* v = (const float*)d_in[2];
  const float* ig = (const float*)d_in[3];
  const float* fg = (const float*)d_in[4];
  float* out = (float*)d_out;

  const int total = in_sizes[0];         // B*NH*S*DH
  const int nchunks = total / (L * DH);  // 2048
  mlstm_mfma<<<dim3(nchunks), dim3(64), 0, stream>>>(q, k, v, ig, fg, out);
}

// Round 16
// 26.935 us; speedup vs baseline: 1.0858x; 1.0858x over previous
//
#include <hip/hip_runtime.h>
#include <hip/hip_bf16.h>
#include <math.h>

namespace {

typedef __bf16 bf16x8 __attribute__((ext_vector_type(8)));
typedef float f32x4 __attribute__((ext_vector_type(4)));

constexpr int L = 64;
constexpr int DH = 64;

// Swizzle key: distinct across BOTH stride-1 and stride-4 row sequences.
__device__ __forceinline__ int kkey(int r) { return (r ^ (r >> 2)) & 7; }
// Byte offset of bf16 element (row,col) in a 64x64 tile, 128B rows,
// 16B-slot XOR swizzle. Used for writes AND reads (both-sides-or-neither).
__device__ __forceinline__ int swz(int row, int col) {
  return row * 128 + ((((col >> 3) ^ kkey(row)) & 7) << 4) + (col & 7) * 2;
}

__device__ __forceinline__ unsigned short bfbits(float f) {
  __bf16 h = (__bf16)f;
  return __builtin_bit_cast(unsigned short, h);
}
__device__ __forceinline__ __bf16 tobf(float f) { return (__bf16)f; }
__device__ __forceinline__ unsigned long long pack4(float a, float b, float c,
                                                    float d) {
  return (unsigned long long)bfbits(a) | ((unsigned long long)bfbits(b) << 16) |
         ((unsigned long long)bfbits(c) << 32) |
         ((unsigned long long)bfbits(d) << 48);
}

// R8 base (best: 26.9us) + two zero-LDS-cost fixes:
//  (1) K loaded COALESCED and staged through the SAME 8KB tile as Q,
//      time-multiplexed (pack K -> read kf -> pack Q -> read qf -> C):
//      removes the last 16-segment fragment-order global loads. Same-array
//      DS ops overlap byte ranges, so the compiler must preserve order.
//  (2) s_setprio(1) around both MFMA clusters (T5): 1-wave blocks are
//      phase-staggered independent waves = the regime where it measured
//      +4-7% (m191), unlike lockstep GEMM.
// LDS stays 17KB -> all 8 grid-blocks/CU resident.
__global__ __launch_bounds__(64, 2) void mlstm_mfma(
    const float* __restrict__ q, const float* __restrict__ k,
    const float* __restrict__ v, const float* __restrict__ ig,
    const float* __restrict__ fg, float* __restrict__ out) {

  __shared__ __align__(16) char qs_raw[64 * 128];  // K bf16 -> Q bf16 -> C
  __shared__ __align__(16) char vt_raw[64 * 128];  // V^T bf16, swizzled
  __shared__ __align__(16) float ea_sh[64];
  __shared__ float eb_sh[64], em_sh[64];

  const int lane = threadIdx.x;
  const int m = lane & 15;   // fragment row/col index
  const int g = lane >> 4;   // fragment k-group
  const size_t cbase = (size_t)blockIdx.x * (L * DH);
  const size_t gb = (size_t)blockIdx.x * L;

  // ======== phase 0: all loads coalesced (gates -> V -> K -> Q) ==========
  const float fgv = fg[gb + lane];
  const float igv = ig[gb + lane];

  const float4* v4 = (const float4*)(v + cbase);
  const float4* k4 = (const float4*)(k + cbase);
  const float4* q4 = (const float4*)(q + cbase);
  float4 vbuf[16], kraw[16], qraw[16];
#pragma unroll
  for (int it = 0; it < 16; ++it) vbuf[it] = v4[it * 64 + lane];
#pragma unroll
  for (int it = 0; it < 16; ++it) kraw[it] = k4[it * 64 + lane];
#pragma unroll
  for (int it = 0; it < 16; ++it) qraw[it] = q4[it * 64 + lane];

  // ======== gate scan (needs only fg/ig — first arrivals) ================
  {
    const float lf = fminf(fgv, 0.f) - log1pf(__expf(-fabsf(fgv)));
    float cum = lf;
#pragma unroll
    for (int o = 1; o < 64; o <<= 1) {
      const float t = __shfl_up(cum, o, 64);
      if (lane >= o) cum += t;
    }
    const float a = igv - cum;
    float b = a;
#pragma unroll
    for (int o = 1; o < 64; o <<= 1) {
      const float t = __shfl_up(b, o, 64);
      if (lane >= o) b = fmaxf(b, t);
    }
    const float bmax = __shfl(b, 63, 64);
    ea_sh[lane] = 0.125f * __expf(a - bmax);  // fold 1/sqrt(DH)
    eb_sh[lane] = __expf(bmax - b);
    em_sh[lane] = __expf(-(b + cum));
  }

  // ======== V^T scatter into LDS (bf16, swizzled) ========================
  {
    unsigned short* vt = (unsigned short*)vt_raw;
#pragma unroll
    for (int it = 0; it < 16; ++it) {
      const int idx = it * 64 + lane;  // float4 index in the chunk
      const int j = idx >> 4;          // time index
      const int d0 = (idx & 15) * 4;   // feature
      vt[swz(d0 + 0, j) >> 1] = bfbits(vbuf[it].x);
      vt[swz(d0 + 1, j) >> 1] = bfbits(vbuf[it].y);
      vt[swz(d0 + 2, j) >> 1] = bfbits(vbuf[it].z);
      vt[swz(d0 + 3, j) >> 1] = bfbits(vbuf[it].w);
    }
  }

  // ======== K stage: coalesced rows -> swizzled bf16 tile ================
#pragma unroll
  for (int it = 0; it < 16; ++it) {
    const int idx = it * 64 + lane;
    const int row = idx >> 4;
    const int col = (idx & 15) * 4;
    *(unsigned long long*)(qs_raw + swz(row, col)) =
        pack4(kraw[it].x, kraw[it].y, kraw[it].z, kraw[it].w);
  }

  // ======== K fragments from LDS (b128, <=2-way conflicts) ===============
  bf16x8 kf[4][2];
#pragma unroll
  for (int rb = 0; rb < 4; ++rb)
#pragma unroll
    for (int kb = 0; kb < 2; ++kb)
      kf[rb][kb] =
          *(const bf16x8*)(qs_raw + swz(rb * 16 + m, kb * 32 + g * 8));

  // ======== Q stage over the same tile (WAR: kf reads precede, in-order) =
#pragma unroll
  for (int it = 0; it < 16; ++it) {
    const int idx = it * 64 + lane;
    const int row = idx >> 4;
    const int col = (idx & 15) * 4;
    *(unsigned long long*)(qs_raw + swz(row, col)) =
        pack4(qraw[it].x, qraw[it].y, qraw[it].z, qraw[it].w);
  }

  // ======== Q fragments from LDS =========================================
  bf16x8 qf[4][2];
#pragma unroll
  for (int cb = 0; cb < 4; ++cb)
#pragma unroll
    for (int kb = 0; kb < 2; ++kb)
      qf[cb][kb] =
          *(const bf16x8*)(qs_raw + swz(cb * 16 + m, kb * 32 + g * 8));

  // ======== V^T fragments (consumed after gating) ========================
  bf16x8 vfr[4][2];
#pragma unroll
  for (int db = 0; db < 4; ++db)
#pragma unroll
    for (int jb = 0; jb < 2; ++jb)
      vfr[db][jb] =
          *(const bf16x8*)(vt_raw + swz(db * 16 + m, jb * 32 + g * 8));

  // ======== mm1: S^T tiles (only rb <= cb are causal) ====================
  f32x4 st[4][4];
  __builtin_amdgcn_s_setprio(1);
#pragma unroll
  for (int cb = 0; cb < 4; ++cb)
#pragma unroll
    for (int rb = 0; rb < 4; ++rb) {
      if (rb > cb) continue;
      f32x4 acc = {0.f, 0.f, 0.f, 0.f};
      acc = __builtin_amdgcn_mfma_f32_16x16x32_bf16(kf[rb][0], qf[cb][0], acc, 0, 0, 0);
      acc = __builtin_amdgcn_mfma_f32_16x16x32_bf16(kf[rb][1], qf[cb][1], acc, 0, 0, 0);
      st[rb][cb] = acc;
    }
  __builtin_amdgcn_s_setprio(0);

  // ======== gating, row-sum, normalizer; write C over the tile ===========
  float ea_j[4][4];
#pragma unroll
  for (int rb = 0; rb < 4; ++rb) {
    const float4 ea4 = *(const float4*)&ea_sh[rb * 16 + g * 4];
    ea_j[rb][0] = ea4.x; ea_j[rb][1] = ea4.y;
    ea_j[rb][2] = ea4.z; ea_j[rb][3] = ea4.w;
  }

  float invr[4];
#pragma unroll
  for (int cb = 0; cb < 4; ++cb) {
    const int i = cb * 16 + m;
    const float ebv = eb_sh[i];
    float rs = 0.f;
    const int rbfill = cb | 1;  // zero-fill the jb ranges mm2 will read
#pragma unroll
    for (int rb = 0; rb < 4; ++rb) {
      if (rb > rbfill) continue;
      unsigned long long wp = 0ull;
      if (rb <= cb) {
        float vv[4];
#pragma unroll
        for (int e = 0; e < 4; ++e) {
          const int j = rb * 16 + g * 4 + e;
          vv[e] = (j <= i) ? st[rb][cb][e] * ea_j[rb][e] * ebv : 0.f;
          rs += vv[e];
        }
        wp = pack4(vv[0], vv[1], vv[2], vv[3]);
      }
      *(unsigned long long*)(qs_raw + swz(i, rb * 16 + g * 4)) = wp;
    }
    rs += __shfl_xor(rs, 16, 64);
    rs += __shfl_xor(rs, 32, 64);
    const float n = fmaxf(fabsf(rs), em_sh[i]);
    invr[cb] = 1.f / (n + 1e-6f);
  }

  // ======== mm2 (per-ib): H^T = V^T * C^T, scale + store ==================
#pragma unroll
  for (int ib = 0; ib < 4; ++ib) {
    const int i = ib * 16 + m;
    const bf16x8 c0 = *(const bf16x8*)(qs_raw + swz(i, g * 8));
    f32x4 acc[4];
    __builtin_amdgcn_s_setprio(1);
#pragma unroll
    for (int db = 0; db < 4; ++db) {
      f32x4 z = {0.f, 0.f, 0.f, 0.f};
      acc[db] = __builtin_amdgcn_mfma_f32_16x16x32_bf16(vfr[db][0], c0, z, 0, 0, 0);
    }
    if (ib >= 2) {
      const bf16x8 c1 = *(const bf16x8*)(qs_raw + swz(i, 32 + g * 8));
#pragma unroll
      for (int db = 0; db < 4; ++db)
        acc[db] = __builtin_amdgcn_mfma_f32_16x16x32_bf16(vfr[db][1], c1, acc[db], 0, 0, 0);
    }
    __builtin_amdgcn_s_setprio(0);
    const float iv = invr[ib];
    float* op = out + cbase + i * 64 + g * 4;
#pragma unroll
    for (int db = 0; db < 4; ++db) {
      const f32x4 hv = acc[db];
      *(float4*)(op + db * 16) =
          make_float4(hv[0] * iv, hv[1] * iv, hv[2] * iv, hv[3] * iv);
    }
  }
}

}  // namespace

extern "C" void kernel_launch(void* const* d_in, const int* in_sizes, int n_in,
                              void* d_out, int out_size, void* d_ws,
                              size_t ws_size, hipStream_t stream) {
  const float* q = (const float*)d_in[0];
  const float* k = (const float*)d_in[1];
  const float* v = (const float*)d_in[2];
  const float* ig = (const float*)d_in[3];
  const float* fg = (const float*)d_in[4];
  float* out = (float*)d_out;

  const int total = in_sizes[0];         // B*NH*S*DH
  const int nchunks = total / (L * DH);  // 2048
  mlstm_mfma<<<dim3(nchunks), dim3(64), 0, stream>>>(q, k, v, ig, fg, out);
}